// Round 6
// baseline (121.167 us; speedup 1.0000x reference)
//
#include <hip/hip_runtime.h>

#define N_ELEM 4096
#define BLOCK 256
#define PER 16             // elems per thread per row
#define NG (PER / 2)       // v2f groups per thread per row = 8
#define NWAVE (BLOCK / 64) // 4
#define ROWS 2             // two rows per block (w shared, overhead halved)
#define CAPACITY 600.0f
#define DAMPING 1e-3f
// R15: REVERT all R14 semantic changes to R13's proven path; keep only
// structural wins. R14 post-mortem: shipped AB2 identity was WRONG
// (A^2+B^2 = D + 2mu*s exactly, NOT D+2mu*s+2mu^2) -> H inflated 25% on
// transition elements -> Schur overshoot + emit-refine w/H short by 20%
// where dx/dlam ~ w/(8mu) ~ 125; plus looser gate (1e-4) + one less warmup
// Newton, four changes at once -> absmax 0.031. R15 semantics == R13:
//   3 Newtons at mu=1, x(1/4) ladder to 0.0039, mu=1e-3 thereafter,
//   gate |dlam|<1e-5 at it>=9 (never fired in R13 -> deterministic 18
//   evals), last eval is the refine point: out = x(lam) - dlam*w/H.
// Structural (each bounded <=~1e-4 output impact vs R13):
//   - 2 rows/block: w/w^2 shared, ONE reduce4+barrier serves both rows,
//     2 independent dependency chains hide sqrt/rcp latency
//   - no per-element state across iters; emit pass recomputes x, w/H
//   - merged rcp: rq = rcp(den*AB2) gives 1/den (as rq*AB2, AB2 cancels
//     EXACTLY in x') and 1/AB2 (as rq*den): 2 trans/elem instead of 3
//   - corrected identity AB2 = D + 2mu*s (one fma; verified by expansion)
#define NITER 18           // == R13's 17 in-loop evals + 1 refine eval
#define N_MU1 3
#define FIRST_FINAL 7      // first it with mu = DAMPING
#define GATE_IT 9
#define GATE_EPS 1e-5f     // below noise floor: never fires (R13-proven)

typedef float v2f __attribute__((ext_vector_type(2)));
union F4V2 { float4 f4; v2f v[2]; };

__device__ __forceinline__ float raw_rcp(float a)  { return __builtin_amdgcn_rcpf(a); }
__device__ __forceinline__ float raw_sqrt(float a) { return __builtin_amdgcn_sqrtf(a); }
__device__ __forceinline__ v2f pk_rcp(v2f a) {
    v2f r; r.x = raw_rcp(a.x); r.y = raw_rcp(a.y); return r;
}
__device__ __forceinline__ v2f pk_sqrt(v2f a) {
    v2f r; r.x = raw_sqrt(a.x); r.y = raw_sqrt(a.y); return r;
}
__device__ __forceinline__ v2f pk_copysign(v2f m, v2f s) {
    v2f r; r.x = __builtin_copysignf(m.x, s.x); r.y = __builtin_copysignf(m.y, s.y);
    return r;
}
__device__ __forceinline__ float bcast_first(float v) {
    return __uint_as_float(__builtin_amdgcn_readfirstlane(__float_as_uint(v)));
}

// Fused 4-value block sum-reduction; ONE barrier; results uniform on all
// threads (stage-2 reads buf[0..3] are whole-wave broadcasts, conflict-free).
__device__ __forceinline__ void block_reduce4(float& a, float& b, float& c,
                                              float& d, float4* buf) {
    #pragma unroll
    for (int off = 32; off > 0; off >>= 1) {
        a += __shfl_xor(a, off, 64);
        b += __shfl_xor(b, off, 64);
        c += __shfl_xor(c, off, 64);
        d += __shfl_xor(d, off, 64);
    }
    const int wave = threadIdx.x >> 6;
    if ((threadIdx.x & 63) == 0) { float4 p = {a, b, c, d}; buf[wave] = p; }
    __syncthreads();
    float4 p = buf[0];
    #pragma unroll
    for (int i = 1; i < NWAVE; ++i) {
        float4 q = buf[i];
        p.x += q.x; p.y += q.y; p.z += q.z; p.w += q.w;
    }
    a = p.x; b = p.y; c = p.z; d = p.w;
}

// Layout: w, cA, cB in registers (48 VGPR data); NO per-element state
// across iterations. Per iter: pure-VALU pass (2 rows interleaved), one
// reduce4/barrier, scalar lam updates. LDS = 128 B reduce scratch.
__global__ __launch_bounds__(BLOCK, 4) void ipm_knapsack_kernel(
        const float* __restrict__ costs,
        const float* __restrict__ weights,
        float* __restrict__ out) {
    __shared__ float4 ldsR[2][NWAVE];     // parity-buffered reduce scratch
    const int rowA = 2 * blockIdx.x;
    const int t    = threadIdx.x;

    v2f w[NG], cA[NG], cB[NG];

    // ---- Load w and both rows' c (negated) into registers ----
    const float4* wg  = reinterpret_cast<const float4*>(weights);
    const float4* cga = reinterpret_cast<const float4*>(costs + (size_t)rowA * N_ELEM);
    const float4* cgb = reinterpret_cast<const float4*>(costs + (size_t)(rowA + 1) * N_ELEM);
    #pragma unroll
    for (int j = 0; j < NG / 2; ++j) {
        F4V2 ww, ca, cb;
        ww.f4 = wg[t + BLOCK * j];
        ca.f4 = cga[t + BLOCK * j];
        cb.f4 = cgb[t + BLOCK * j];
        ca.f4.x = -ca.f4.x; ca.f4.y = -ca.f4.y; ca.f4.z = -ca.f4.z; ca.f4.w = -ca.f4.w;
        cb.f4.x = -cb.f4.x; cb.f4.y = -cb.f4.y; cb.f4.z = -cb.f4.z; cb.f4.w = -cb.f4.w;
        w[2 * j] = ww.v[0];  w[2 * j + 1] = ww.v[1];
        cA[2 * j] = ca.v[0]; cA[2 * j + 1] = ca.v[1];
        cB[2 * j] = cb.v[0]; cB[2 * j + 1] = cb.v[1];
    }

    float lamA = 0.0f, lamB = 0.0f, dlA = 0.0f, dlB = 0.0f;

    // Per-element core. Quadratic r x^2 - (r+2mu) x + mu = 0; disc D =
    // r^2 + 4mu^2 exactly. den = |r|+2mu+sqrt(D) > 0 (no cancellation);
    // x' = 2mu/den in (0,0.5]; x = 0.5 - copysign(0.5-x', r).
    // H*mu = A^2+B^2 = D + 2mu*s (A=den/2, B=A-|r|; verified identity).
    // rq = rcp(den*AB2): x' = 2mu*(rq*AB2) (AB2 cancels exactly);
    // 1/AB2 = rq*den for the Schur sum.
    #define ELEM_CORE(r_, wk_, wsq_, s0_, s2_)                                 \
        {                                                                      \
            const v2f a_   = __builtin_elementwise_abs(r_);                    \
            const v2f D_   = r_ * r_ + mu4sq;                                  \
            const v2f s_   = pk_sqrt(D_);                                      \
            const v2f den_ = (a_ + two_mu) + s_;                               \
            const v2f AB2_ = two_mu * s_ + D_;                                 \
            const v2f rq_  = pk_rcp(den_ * AB2_);                              \
            const v2f xp_  = two_mu * (rq_ * AB2_);                            \
            const v2f xk_  = 0.5f - pk_copysign(0.5f - xp_, r_);               \
            s0_ = wk_ * xk_ + s0_;                                             \
            s2_ = wsq_ * (rq_ * den_) + s2_;                                   \
        }

    for (int it = 0; it < NITER; ++it) {
        // mu: 1,1,1, .25, .0625, .015625, .00390625, then DAMPING forever.
        const float mu = (it < N_MU1) ? 1.0f
                       : (it < FIRST_FINAL)
                         ? __uint_as_float((unsigned)(127 - 2 * (it - (N_MU1 - 1))) << 23)
                         : DAMPING;
        const float two_mu = 2.0f * mu;
        const float mu4sq  = 4.0f * mu * mu;

        v2f s0a = {0.0f, 0.0f}, s2a = {0.0f, 0.0f};
        v2f s0b = {0.0f, 0.0f}, s2b = {0.0f, 0.0f};
        #pragma unroll
        for (int k = 0; k < NG; ++k) {
            const v2f wk  = w[k];
            const v2f wsq = wk * wk;
            const v2f ra  = lamA * wk + cA[k];
            const v2f rb  = lamB * wk + cB[k];
            ELEM_CORE(ra, wk, wsq, s0a, s2a);
            ELEM_CORE(rb, wk, wsq, s0b, s2b);
        }
        float s0A = s0a.x + s0a.y, s2A = s2a.x + s2a.y;
        float s0B = s0b.x + s0b.y, s2B = s2b.x + s2b.y;
        block_reduce4(s0A, s2A, s0B, s2B, ldsR[it & 1]);   // ONE barrier/iter
        // Schur denom = sum w^2/H = mu * sum w^2/AB2
        dlA = bcast_first((s0A - CAPACITY) * raw_rcp(mu * s2A));
        dlB = bcast_first((s0B - CAPACITY) * raw_rcp(mu * s2B));

        // Break WITHOUT applying dlam: the (lam, dlam) pair feeds the emit
        // refine. Gate below noise floor (R13-proven) => deterministic 18
        // evals; kept only for free upside. Uniform branch.
        if ((it >= GATE_IT && fmaxf(fabsf(dlA), fabsf(dlB)) < GATE_EPS) ||
            it == NITER - 1) break;
        lamA += dlA; lamB += dlB;
    }
    #undef ELEM_CORE

    // ---- Emit pass: recompute x, w/H at (lam, mu=DAMPING); refine:
    // out = x - dlam * w/H  (== reference _kkt_refine with F1 == 0).
    {
        const float mu = DAMPING;
        const float two_mu = 2.0f * mu;
        const float mu4sq  = 4.0f * mu * mu;
        float4* oA = reinterpret_cast<float4*>(out + (size_t)rowA * N_ELEM);
        float4* oB = reinterpret_cast<float4*>(out + (size_t)(rowA + 1) * N_ELEM);
        #pragma unroll
        for (int j = 0; j < NG / 2; ++j) {
            F4V2 ovA, ovB;
            #pragma unroll
            for (int h = 0; h < 2; ++h) {
                const int k = 2 * j + h;
                const v2f wk  = w[k];
                const v2f muw = mu * wk;
                {
                    const v2f r_   = lamA * wk + cA[k];
                    const v2f a_   = __builtin_elementwise_abs(r_);
                    const v2f D_   = r_ * r_ + mu4sq;
                    const v2f s_   = pk_sqrt(D_);
                    const v2f den_ = (a_ + two_mu) + s_;
                    const v2f AB2_ = two_mu * s_ + D_;
                    const v2f rq_  = pk_rcp(den_ * AB2_);
                    const v2f xp_  = two_mu * (rq_ * AB2_);
                    const v2f xk_  = 0.5f - pk_copysign(0.5f - xp_, r_);
                    const v2f wi_  = muw * (rq_ * den_);
                    ovA.v[h] = xk_ - dlA * wi_;
                }
                {
                    const v2f r_   = lamB * wk + cB[k];
                    const v2f a_   = __builtin_elementwise_abs(r_);
                    const v2f D_   = r_ * r_ + mu4sq;
                    const v2f s_   = pk_sqrt(D_);
                    const v2f den_ = (a_ + two_mu) + s_;
                    const v2f AB2_ = two_mu * s_ + D_;
                    const v2f rq_  = pk_rcp(den_ * AB2_);
                    const v2f xp_  = two_mu * (rq_ * AB2_);
                    const v2f xk_  = 0.5f - pk_copysign(0.5f - xp_, r_);
                    const v2f wi_  = muw * (rq_ * den_);
                    ovB.v[h] = xk_ - dlB * wi_;
                }
            }
            oA[t + BLOCK * j] = ovA.f4;
            oB[t + BLOCK * j] = ovB.f4;
        }
    }
}

extern "C" void kernel_launch(void* const* d_in, const int* in_sizes, int n_in,
                              void* d_out, int out_size, void* d_ws, size_t ws_size,
                              hipStream_t stream) {
    const float* costs   = (const float*)d_in[0];
    const float* weights = (const float*)d_in[1];
    float* out = (float*)d_out;
    const int B = in_sizes[0] / N_ELEM;   // 2048 rows
    ipm_knapsack_kernel<<<B / ROWS, BLOCK, 0, stream>>>(costs, weights, out);
}

// Round 7
// 119.978 us; speedup vs baseline: 1.0099x; 1.0099x over previous
//
#include <hip/hip_runtime.h>

#define N_ELEM 4096
#define BLOCK 256
#define PER 16             // elems per thread per row
#define NG (PER / 2)       // v2f groups per thread per row = 8
#define NWAVE (BLOCK / 64) // 4
#define ROWS 2             // two rows per block (w shared, overhead halved)
#define CAPACITY 600.0f
#define DAMPING 1e-3f
// R16: ONE isolated change vs R15 (the passing control): NITER 18 -> 13.
// Rationale: the |dlam|<1e-5 gate never fires (below fp32 noise floor of
// sum(w*x)~600 -> dlam floor ~2e-5; absmax bit-identical across R13/R15),
// so R15 deterministically ran 11 evals at the final mu. With the EXACT
// per-element coordinate solve, lam-Newton at fixed mu converges
// quadratically once the ladder hands over at mu=0.0039 (lam err ~1e-2):
// 2-3 Newtons reach the noise floor; the other ~8 were noise-bouncing.
// New schedule: 3 warmup (mu=1) + 4 ladder (x1/4 to 0.0039) + 5 applied
// final-mu Newtons + refine eval = 13. R14's failure was the WRONG AB2
// identity bundled with schedule cuts; AB2 = D + 2mu*s is now verified.
// R15 post-mortem (kept for the record): 2 rows/block cut total busy
// cycles ~12% but occupancy fell 30->25% and latency exposure ate the
// win — time ≈ evals × per-eval cost; evals are the lever.
#define NITER 13
#define N_MU1 3
#define FIRST_FINAL 7      // first it with mu = DAMPING
#define GATE_IT 9
#define GATE_EPS 1e-5f     // below noise floor: never fires (kept, free upside)

typedef float v2f __attribute__((ext_vector_type(2)));
union F4V2 { float4 f4; v2f v[2]; };

__device__ __forceinline__ float raw_rcp(float a)  { return __builtin_amdgcn_rcpf(a); }
__device__ __forceinline__ float raw_sqrt(float a) { return __builtin_amdgcn_sqrtf(a); }
__device__ __forceinline__ v2f pk_rcp(v2f a) {
    v2f r; r.x = raw_rcp(a.x); r.y = raw_rcp(a.y); return r;
}
__device__ __forceinline__ v2f pk_sqrt(v2f a) {
    v2f r; r.x = raw_sqrt(a.x); r.y = raw_sqrt(a.y); return r;
}
__device__ __forceinline__ v2f pk_copysign(v2f m, v2f s) {
    v2f r; r.x = __builtin_copysignf(m.x, s.x); r.y = __builtin_copysignf(m.y, s.y);
    return r;
}
__device__ __forceinline__ float bcast_first(float v) {
    return __uint_as_float(__builtin_amdgcn_readfirstlane(__float_as_uint(v)));
}

// Fused 4-value block sum-reduction; ONE barrier; results uniform on all
// threads (stage-2 reads buf[0..3] are whole-wave broadcasts, conflict-free).
__device__ __forceinline__ void block_reduce4(float& a, float& b, float& c,
                                              float& d, float4* buf) {
    #pragma unroll
    for (int off = 32; off > 0; off >>= 1) {
        a += __shfl_xor(a, off, 64);
        b += __shfl_xor(b, off, 64);
        c += __shfl_xor(c, off, 64);
        d += __shfl_xor(d, off, 64);
    }
    const int wave = threadIdx.x >> 6;
    if ((threadIdx.x & 63) == 0) { float4 p = {a, b, c, d}; buf[wave] = p; }
    __syncthreads();
    float4 p = buf[0];
    #pragma unroll
    for (int i = 1; i < NWAVE; ++i) {
        float4 q = buf[i];
        p.x += q.x; p.y += q.y; p.z += q.z; p.w += q.w;
    }
    a = p.x; b = p.y; c = p.z; d = p.w;
}

// Layout: w, cA, cB in registers (48 VGPR data); NO per-element state
// across iterations. Per iter: pure-VALU pass (2 rows interleaved), one
// reduce4/barrier, scalar lam updates. LDS = 128 B reduce scratch.
__global__ __launch_bounds__(BLOCK, 4) void ipm_knapsack_kernel(
        const float* __restrict__ costs,
        const float* __restrict__ weights,
        float* __restrict__ out) {
    __shared__ float4 ldsR[2][NWAVE];     // parity-buffered reduce scratch
    const int rowA = 2 * blockIdx.x;
    const int t    = threadIdx.x;

    v2f w[NG], cA[NG], cB[NG];

    // ---- Load w and both rows' c (negated) into registers ----
    const float4* wg  = reinterpret_cast<const float4*>(weights);
    const float4* cga = reinterpret_cast<const float4*>(costs + (size_t)rowA * N_ELEM);
    const float4* cgb = reinterpret_cast<const float4*>(costs + (size_t)(rowA + 1) * N_ELEM);
    #pragma unroll
    for (int j = 0; j < NG / 2; ++j) {
        F4V2 ww, ca, cb;
        ww.f4 = wg[t + BLOCK * j];
        ca.f4 = cga[t + BLOCK * j];
        cb.f4 = cgb[t + BLOCK * j];
        ca.f4.x = -ca.f4.x; ca.f4.y = -ca.f4.y; ca.f4.z = -ca.f4.z; ca.f4.w = -ca.f4.w;
        cb.f4.x = -cb.f4.x; cb.f4.y = -cb.f4.y; cb.f4.z = -cb.f4.z; cb.f4.w = -cb.f4.w;
        w[2 * j] = ww.v[0];  w[2 * j + 1] = ww.v[1];
        cA[2 * j] = ca.v[0]; cA[2 * j + 1] = ca.v[1];
        cB[2 * j] = cb.v[0]; cB[2 * j + 1] = cb.v[1];
    }

    float lamA = 0.0f, lamB = 0.0f, dlA = 0.0f, dlB = 0.0f;

    // Per-element core. Quadratic r x^2 - (r+2mu) x + mu = 0; disc D =
    // r^2 + 4mu^2 exactly. den = |r|+2mu+sqrt(D) > 0 (no cancellation);
    // x' = 2mu/den in (0,0.5]; x = 0.5 - copysign(0.5-x', r).
    // H*mu = A^2+B^2 = D + 2mu*s (A=den/2, B=A-|r|; verified identity).
    // rq = rcp(den*AB2): x' = 2mu*(rq*AB2) (AB2 cancels exactly);
    // 1/AB2 = rq*den for the Schur sum.
    #define ELEM_CORE(r_, wk_, wsq_, s0_, s2_)                                 \
        {                                                                      \
            const v2f a_   = __builtin_elementwise_abs(r_);                    \
            const v2f D_   = r_ * r_ + mu4sq;                                  \
            const v2f s_   = pk_sqrt(D_);                                      \
            const v2f den_ = (a_ + two_mu) + s_;                               \
            const v2f AB2_ = two_mu * s_ + D_;                                 \
            const v2f rq_  = pk_rcp(den_ * AB2_);                              \
            const v2f xp_  = two_mu * (rq_ * AB2_);                            \
            const v2f xk_  = 0.5f - pk_copysign(0.5f - xp_, r_);               \
            s0_ = wk_ * xk_ + s0_;                                             \
            s2_ = wsq_ * (rq_ * den_) + s2_;                                   \
        }

    for (int it = 0; it < NITER; ++it) {
        // mu: 1,1,1, .25, .0625, .015625, .00390625, then DAMPING forever.
        const float mu = (it < N_MU1) ? 1.0f
                       : (it < FIRST_FINAL)
                         ? __uint_as_float((unsigned)(127 - 2 * (it - (N_MU1 - 1))) << 23)
                         : DAMPING;
        const float two_mu = 2.0f * mu;
        const float mu4sq  = 4.0f * mu * mu;

        v2f s0a = {0.0f, 0.0f}, s2a = {0.0f, 0.0f};
        v2f s0b = {0.0f, 0.0f}, s2b = {0.0f, 0.0f};
        #pragma unroll
        for (int k = 0; k < NG; ++k) {
            const v2f wk  = w[k];
            const v2f wsq = wk * wk;
            const v2f ra  = lamA * wk + cA[k];
            const v2f rb  = lamB * wk + cB[k];
            ELEM_CORE(ra, wk, wsq, s0a, s2a);
            ELEM_CORE(rb, wk, wsq, s0b, s2b);
        }
        float s0A = s0a.x + s0a.y, s2A = s2a.x + s2a.y;
        float s0B = s0b.x + s0b.y, s2B = s2b.x + s2b.y;
        block_reduce4(s0A, s2A, s0B, s2B, ldsR[it & 1]);   // ONE barrier/iter
        // Schur denom = sum w^2/H = mu * sum w^2/AB2
        dlA = bcast_first((s0A - CAPACITY) * raw_rcp(mu * s2A));
        dlB = bcast_first((s0B - CAPACITY) * raw_rcp(mu * s2B));

        // Break WITHOUT applying dlam: the (lam, dlam) pair feeds the emit
        // refine. Gate below noise floor (never fires) => deterministic 13
        // evals; kept only for free upside. Uniform branch.
        if ((it >= GATE_IT && fmaxf(fabsf(dlA), fabsf(dlB)) < GATE_EPS) ||
            it == NITER - 1) break;
        lamA += dlA; lamB += dlB;
    }
    #undef ELEM_CORE

    // ---- Emit pass: recompute x, w/H at (lam, mu=DAMPING); refine:
    // out = x - dlam * w/H  (== reference _kkt_refine with F1 == 0).
    {
        const float mu = DAMPING;
        const float two_mu = 2.0f * mu;
        const float mu4sq  = 4.0f * mu * mu;
        float4* oA = reinterpret_cast<float4*>(out + (size_t)rowA * N_ELEM);
        float4* oB = reinterpret_cast<float4*>(out + (size_t)(rowA + 1) * N_ELEM);
        #pragma unroll
        for (int j = 0; j < NG / 2; ++j) {
            F4V2 ovA, ovB;
            #pragma unroll
            for (int h = 0; h < 2; ++h) {
                const int k = 2 * j + h;
                const v2f wk  = w[k];
                const v2f muw = mu * wk;
                {
                    const v2f r_   = lamA * wk + cA[k];
                    const v2f a_   = __builtin_elementwise_abs(r_);
                    const v2f D_   = r_ * r_ + mu4sq;
                    const v2f s_   = pk_sqrt(D_);
                    const v2f den_ = (a_ + two_mu) + s_;
                    const v2f AB2_ = two_mu * s_ + D_;
                    const v2f rq_  = pk_rcp(den_ * AB2_);
                    const v2f xp_  = two_mu * (rq_ * AB2_);
                    const v2f xk_  = 0.5f - pk_copysign(0.5f - xp_, r_);
                    const v2f wi_  = muw * (rq_ * den_);
                    ovA.v[h] = xk_ - dlA * wi_;
                }
                {
                    const v2f r_   = lamB * wk + cB[k];
                    const v2f a_   = __builtin_elementwise_abs(r_);
                    const v2f D_   = r_ * r_ + mu4sq;
                    const v2f s_   = pk_sqrt(D_);
                    const v2f den_ = (a_ + two_mu) + s_;
                    const v2f AB2_ = two_mu * s_ + D_;
                    const v2f rq_  = pk_rcp(den_ * AB2_);
                    const v2f xp_  = two_mu * (rq_ * AB2_);
                    const v2f xk_  = 0.5f - pk_copysign(0.5f - xp_, r_);
                    const v2f wi_  = muw * (rq_ * den_);
                    ovB.v[h] = xk_ - dlB * wi_;
                }
            }
            oA[t + BLOCK * j] = ovA.f4;
            oB[t + BLOCK * j] = ovB.f4;
        }
    }
}

extern "C" void kernel_launch(void* const* d_in, const int* in_sizes, int n_in,
                              void* d_out, int out_size, void* d_ws, size_t ws_size,
                              hipStream_t stream) {
    const float* costs   = (const float*)d_in[0];
    const float* weights = (const float*)d_in[1];
    float* out = (float*)d_out;
    const int B = in_sizes[0] / N_ELEM;   // 2048 rows
    ipm_knapsack_kernel<<<B / ROWS, BLOCK, 0, stream>>>(costs, weights, out);
}